// Round 9
// baseline (188.952 us; speedup 1.0000x reference)
//
#include <hip/hip_runtime.h>
#include <math.h>

#define C 128

typedef __attribute__((ext_vector_type(8))) short short8;
typedef __attribute__((ext_vector_type(4))) float f32x4;
typedef __attribute__((ext_vector_type(4))) unsigned short ushort4_t;
typedef __attribute__((ext_vector_type(8))) unsigned short ushort8_t;

__device__ inline unsigned short f2b(float f) {
    union { float f; unsigned int u; } v; v.f = f;
    unsigned int u = v.u;
    return (unsigned short)((u + 0x7FFFu + ((u >> 16) & 1u)) >> 16);  // RNE
}
__device__ inline float bits2f(unsigned int u) {
    union { unsigned int u; float f; } v; v.u = u; return v.f;
}

// accumulate 8 bf16 (packed in uint4) scaled by s into a[0..7]
__device__ inline void acc8(float* a, uint4 u, float s) {
    a[0] += s * bits2f(u.x << 16); a[1] += s * bits2f(u.x & 0xFFFF0000u);
    a[2] += s * bits2f(u.y << 16); a[3] += s * bits2f(u.y & 0xFFFF0000u);
    a[4] += s * bits2f(u.z << 16); a[5] += s * bits2f(u.z & 0xFFFF0000u);
    a[6] += s * bits2f(u.w << 16); a[7] += s * bits2f(u.w & 0xFFFF0000u);
}

// ---------------- shared row worker: aggregate + bias + LN + GELU ----------------
// 8 lanes cooperate on one row; this lane covers 16 cols c0..c0+15. Result in t[16].
__device__ inline void agg_ln_gelu_row16(
    int row, int c0,
    const int* __restrict__ rowbeg, const int* __restrict__ rowend,
    const int2* __restrict__ edata, const unsigned short* __restrict__ Hb,
    const float* __restrict__ dis, const float* __restrict__ bias,
    const float* __restrict__ g, const float* __restrict__ beta, float* t) {
    float a[16];
    #pragma unroll
    for (int j = 0; j < 16; ++j) a[j] = 0.f;

    // self-loop: dis^2 * Hb[row]
    {
        float d = dis[row];
        const unsigned short* hr = Hb + (size_t)row * C + c0;
        uint4 h0 = *(const uint4*)(hr);
        uint4 h1 = *(const uint4*)(hr + 8);
        acc8(a, h0, d * d);
        acc8(a + 8, h1, d * d);
    }

    int ei = rowbeg[row];
    const int ee = rowend[row];
    for (; ei + 1 < ee; ei += 2) {
        int2 e0 = edata[ei];
        int2 e1 = edata[ei + 1];
        const unsigned short* p0 = Hb + (size_t)e0.x * C + c0;
        const unsigned short* p1 = Hb + (size_t)e1.x * C + c0;
        uint4 u00 = *(const uint4*)(p0);
        uint4 u01 = *(const uint4*)(p0 + 8);
        uint4 u10 = *(const uint4*)(p1);
        uint4 u11 = *(const uint4*)(p1 + 8);
        float w0 = bits2f((unsigned int)e0.y);
        float w1 = bits2f((unsigned int)e1.y);
        acc8(a, u00, w0); acc8(a + 8, u01, w0);
        acc8(a, u10, w1); acc8(a + 8, u11, w1);
    }
    if (ei < ee) {
        int2 e0 = edata[ei];
        const unsigned short* p0 = Hb + (size_t)e0.x * C + c0;
        uint4 u00 = *(const uint4*)(p0);
        uint4 u01 = *(const uint4*)(p0 + 8);
        float w0 = bits2f((unsigned int)e0.y);
        acc8(a, u00, w0); acc8(a + 8, u01, w0);
    }

    // + bias
    #pragma unroll
    for (int q = 0; q < 4; ++q) {
        float4 bv = *(const float4*)(bias + c0 + q * 4);
        a[q * 4 + 0] += bv.x; a[q * 4 + 1] += bv.y;
        a[q * 4 + 2] += bv.z; a[q * 4 + 3] += bv.w;
    }

    // LayerNorm across the 8-lane group (128 cols)
    float s = 0.f, sq = 0.f;
    #pragma unroll
    for (int j = 0; j < 16; ++j) { s += a[j]; sq += a[j] * a[j]; }
    #pragma unroll
    for (int off = 4; off >= 1; off >>= 1) {
        s  += __shfl_xor(s, off, 64);
        sq += __shfl_xor(sq, off, 64);
    }
    float mu = s * (1.0f / C);
    float var = sq * (1.0f / C) - mu * mu;
    float rstd = rsqrtf(var + 1e-5f);

    #pragma unroll
    for (int q = 0; q < 4; ++q) {
        float4 gv = *(const float4*)(g + c0 + q * 4);
        float4 bv = *(const float4*)(beta + c0 + q * 4);
        float gg[4] = {gv.x, gv.y, gv.z, gv.w};
        float bb[4] = {bv.x, bv.y, bv.z, bv.w};
        #pragma unroll
        for (int j = 0; j < 4; ++j) {
            float v = (a[q * 4 + j] - mu) * rstd * gg[j] + bb[j];
            t[q * 4 + j] = 0.5f * v * (1.0f + erff(v * 0.70710678118654752f));
        }
    }
}

// ---------------- gcn_norm + CSR build ----------------

__global__ void k_zero(int* __restrict__ cnt, int* __restrict__ cursor, int n) {
    int i = blockIdx.x * blockDim.x + threadIdx.x;
    if (i < n) cnt[i] = 0;
    if (i == 0) *cursor = 0;
}

__global__ void k_cnt(const int* __restrict__ dst, int* __restrict__ cnt, int e) {
    int i = blockIdx.x * blockDim.x + threadIdx.x;
    if (i < e) atomicAdd(&cnt[dst[i]], 1);
}

__global__ void k_dis_reserve(const int* __restrict__ cnt, float* __restrict__ dis,
                              int* __restrict__ rowbeg, int* __restrict__ rowcur,
                              int* __restrict__ cursor, int n) {
    int i = blockIdx.x * blockDim.x + threadIdx.x;
    if (i < n) {
        dis[i] = rsqrtf((float)cnt[i] + 1.0f);
        int b = atomicAdd(cursor, cnt[i]);
        rowbeg[i] = b;
        rowcur[i] = b;
    }
}

__global__ void k_place(const int* __restrict__ src, const int* __restrict__ dst,
                        const float* __restrict__ ew, const float* __restrict__ dis,
                        int* __restrict__ rowcur, int2* __restrict__ edata, int e) {
    int i = blockIdx.x * blockDim.x + threadIdx.x;
    if (i >= e) return;
    int s = src[i], d = dst[i];
    int p = atomicAdd(&rowcur[d], 1);
    float w = dis[s] * ew[i] * dis[d];
    union { float f; int i; } wb; wb.f = w;
    edata[p] = make_int2(s, wb.i);
}

// ---------------- W pack (both weights in one launch) ----------------
__global__ void k_pack_w2(const float* __restrict__ W1, const float* __restrict__ W2,
                          unsigned short* __restrict__ W1p, unsigned short* __restrict__ W2p) {
    int idx = blockIdx.x * blockDim.x + threadIdx.x;
    const float* W = (idx < C * C) ? W1 : W2;
    unsigned short* Wp = (idx < C * C) ? W1p : W2p;
    int p = idx & (C * C - 1);
    int j = p & 7;
    int l = (p >> 3) & 63;
    int t = p >> 9;           // ct*4 + ks
    int ks = t & 3, ct = t >> 2;
    int k = ks * 32 + ((l >> 4) << 3) + j;
    int c = (ct << 4) + (l & 15);
    Wp[p] = f2b(W[k * C + c]);
}

// ---------------- MFMA GEMM: Hb[n,128](bf16) = bf16(X[n,128]) @ Wp ----------------
__global__ __launch_bounds__(256) void k_gemm_mfma(
    const float* __restrict__ X, const unsigned short* __restrict__ Wp,
    unsigned short* __restrict__ Hb, int n) {
    __shared__ unsigned short xs[32 * C];  // 8 KB, XOR-swizzled
    const int tid = threadIdx.x;
    const int base = blockIdx.x * 32;

    const float4* Xv = (const float4*)(X + (size_t)base * C);
    #pragma unroll
    for (int i = 0; i < 4; ++i) {
        int idx4 = i * 256 + tid;
        int elem = idx4 * 4;
        int r = elem >> 7, c = elem & 127;
        float4 v = make_float4(0.f, 0.f, 0.f, 0.f);
        if (base + r < n) v = Xv[idx4];
        ushort4_t pkt;
        pkt.x = f2b(v.x); pkt.y = f2b(v.y); pkt.z = f2b(v.z); pkt.w = f2b(v.w);
        int byte = (r * 256 + c * 2) ^ ((r & 7) << 4);
        *(ushort4_t*)((char*)xs + byte) = pkt;
    }
    __syncthreads();

    const int lane = tid & 63;
    const int wid = tid >> 6;
    const int wm = wid >> 1;
    const int wn = wid & 1;
    const int arow = wm * 16 + (lane & 15);
    const int kg = lane >> 4;

    f32x4 acc[4] = {f32x4{0,0,0,0}, f32x4{0,0,0,0}, f32x4{0,0,0,0}, f32x4{0,0,0,0}};

    #pragma unroll
    for (int ks = 0; ks < 4; ++ks) {
        int abyte = (arow * 256 + ks * 64 + kg * 16) ^ ((arow & 7) << 4);
        short8 a = *(const short8*)((const char*)xs + abyte);
        #pragma unroll
        for (int nt = 0; nt < 4; ++nt) {
            int ct = wn * 4 + nt;
            short8 b = *(const short8*)(Wp + (size_t)((ct * 4 + ks) * 64 + lane) * 8);
            acc[nt] = __builtin_amdgcn_mfma_f32_16x16x32_bf16(a, b, acc[nt], 0, 0, 0);
        }
    }

    const int rbase = base + wm * 16 + kg * 4;
    #pragma unroll
    for (int nt = 0; nt < 4; ++nt) {
        int col = wn * 64 + nt * 16 + (lane & 15);
        #pragma unroll
        for (int r = 0; r < 4; ++r) {
            int row = rbase + r;
            if (row >= n) continue;
            Hb[(size_t)row * C + col] = f2b(acc[nt][r]);
        }
    }
}

// ---------------- fused: agg+bias+LN+GELU (layer-1 params) -> LDS -> GEMM (W2) ----------------
// 32 rows per block, single pass: 8 lanes/row, 8 rows/wave, 4 waves.
__global__ __launch_bounds__(256) void k_fused_agg_gemm(
    const int* __restrict__ rowbeg, const int* __restrict__ rowend,
    const int2* __restrict__ edata,
    const unsigned short* __restrict__ Hb_in, const float* __restrict__ dis,
    const float* __restrict__ bias, const float* __restrict__ g,
    const float* __restrict__ beta,
    const unsigned short* __restrict__ Wp, unsigned short* __restrict__ Hb_out, int n) {
    __shared__ unsigned short xs[32 * C];  // 8 KB, XOR-swizzled
    const int tid = threadIdx.x;
    const int lane = tid & 63;
    const int wid = tid >> 6;
    const int grp = lane >> 3;          // 8 row-groups per wave
    const int sub = lane & 7;           // 8 lanes per row
    const int base = blockIdx.x * 32;
    const int c0 = sub * 16;

    // phase A: aggregate + LN + GELU 32 rows (one pass), pack bf16 into swizzled LDS
    {
        int r = wid * 8 + grp;
        int row = base + r;
        float t[16];
        #pragma unroll
        for (int j = 0; j < 16; ++j) t[j] = 0.f;
        if (row < n)
            agg_ln_gelu_row16(row, c0, rowbeg, rowend, edata, Hb_in, dis, bias, g, beta, t);
        ushort8_t p0, p1;
        #pragma unroll
        for (int j = 0; j < 8; ++j) { p0[j] = f2b(t[j]); p1[j] = f2b(t[j + 8]); }
        int lin = r * 256 + c0 * 2;
        *(ushort8_t*)((char*)xs + ((lin) ^ ((r & 7) << 4))) = p0;
        *(ushort8_t*)((char*)xs + ((lin + 16) ^ ((r & 7) << 4))) = p1;
    }
    __syncthreads();

    // phase B: MFMA GEMM from LDS
    const int wm = wid >> 1;
    const int wn = wid & 1;
    const int arow = wm * 16 + (lane & 15);
    const int kg = lane >> 4;

    f32x4 acc[4] = {f32x4{0,0,0,0}, f32x4{0,0,0,0}, f32x4{0,0,0,0}, f32x4{0,0,0,0}};

    #pragma unroll
    for (int ks = 0; ks < 4; ++ks) {
        int abyte = (arow * 256 + ks * 64 + kg * 16) ^ ((arow & 7) << 4);
        short8 a = *(const short8*)((const char*)xs + abyte);
        #pragma unroll
        for (int nt = 0; nt < 4; ++nt) {
            int ct = wn * 4 + nt;
            short8 b = *(const short8*)(Wp + (size_t)((ct * 4 + ks) * 64 + lane) * 8);
            acc[nt] = __builtin_amdgcn_mfma_f32_16x16x32_bf16(a, b, acc[nt], 0, 0, 0);
        }
    }

    const int rbase = base + wm * 16 + kg * 4;
    #pragma unroll
    for (int nt = 0; nt < 4; ++nt) {
        int col = wn * 64 + nt * 16 + (lane & 15);
        #pragma unroll
        for (int r = 0; r < 4; ++r) {
            int row = rbase + r;
            if (row >= n) continue;
            Hb_out[(size_t)row * C + col] = f2b(acc[nt][r]);
        }
    }
}

// ---------------- final: aggregate + bias + LN + GELU + residual -> f32 out ----------------
// 8 lanes/row, 8 rows/wave, 32 rows/block.
__global__ __launch_bounds__(256) void k_agg_ln_gelu(
    const int* __restrict__ rowbeg, const int* __restrict__ rowend,
    const int2* __restrict__ edata,
    const unsigned short* __restrict__ Hb, const float* __restrict__ dis,
    const float* __restrict__ bias, const float* __restrict__ g,
    const float* __restrict__ beta, const float* __restrict__ resid,
    float* __restrict__ Out, int n) {
    const int lane = threadIdx.x & 63;
    const int wid = threadIdx.x >> 6;
    const int grp = lane >> 3;
    const int sub = lane & 7;
    const int row = blockIdx.x * 32 + wid * 8 + grp;
    if (row >= n) return;
    const int c0 = sub * 16;

    float t[16];
    agg_ln_gelu_row16(row, c0, rowbeg, rowend, edata, Hb, dis, bias, g, beta, t);

    const float* rp = resid + (size_t)row * C + c0;
    float* op = Out + (size_t)row * C + c0;
    #pragma unroll
    for (int q = 0; q < 4; ++q) {
        float4 rv = *(const float4*)(rp + q * 4);
        *(float4*)(op + q * 4) =
            make_float4(t[q * 4] + rv.x, t[q * 4 + 1] + rv.y,
                        t[q * 4 + 2] + rv.z, t[q * 4 + 3] + rv.w);
    }
}

// ---------------- launch ----------------

extern "C" void kernel_launch(void* const* d_in, const int* in_sizes, int n_in,
                              void* d_out, int out_size, void* d_ws, size_t ws_size,
                              hipStream_t stream) {
    const float* x      = (const float*)d_in[0];
    const int*   eidx   = (const int*)d_in[1];
    const float* ew     = (const float*)d_in[2];
    const float* W1     = (const float*)d_in[3];
    const float* b1     = (const float*)d_in[4];
    const float* g1     = (const float*)d_in[5];
    const float* beta1  = (const float*)d_in[6];
    const float* W2     = (const float*)d_in[7];
    const float* b2     = (const float*)d_in[8];
    const float* g2     = (const float*)d_in[9];
    const float* beta2  = (const float*)d_in[10];

    const int n = in_sizes[0] / C;
    const int e = in_sizes[2];
    const int* src = eidx;
    const int* dst = eidx + e;

    float* out = (float*)d_out;

    // workspace layout (256B-aligned chunks)
    char* p = (char*)d_ws;
    auto alloc = [&](size_t bytes) {
        char* q = p;
        p += (bytes + 255) & ~(size_t)255;
        return q;
    };
    float* dis    = (float*)alloc(sizeof(float) * n);
    int*   cnt    = (int*)alloc(sizeof(int) * n);
    int*   rowbeg = (int*)alloc(sizeof(int) * n);
    int*   rowcur = (int*)alloc(sizeof(int) * n);   // becomes rowend after k_place
    int2*  edata  = (int2*)alloc(sizeof(int2) * e);
    unsigned short* Hb1 = (unsigned short*)alloc(sizeof(unsigned short) * (size_t)n * C);
    unsigned short* Hb2 = (unsigned short*)alloc(sizeof(unsigned short) * (size_t)n * C);
    unsigned short* W1p = (unsigned short*)alloc(sizeof(unsigned short) * C * C);
    unsigned short* W2p = (unsigned short*)alloc(sizeof(unsigned short) * C * C);
    int*   cursor = (int*)alloc(sizeof(int));

    const int B = 256;
    const int gn = (n + B - 1) / B;
    const int ge = (e + B - 1) / B;

    // gcn_norm + CSR
    k_zero<<<gn, B, 0, stream>>>(cnt, cursor, n);
    k_cnt<<<ge, B, 0, stream>>>(dst, cnt, e);
    k_dis_reserve<<<gn, B, 0, stream>>>(cnt, dis, rowbeg, rowcur, cursor, n);
    k_place<<<ge, B, 0, stream>>>(src, dst, ew, dis, rowcur, edata, e);

    // pack weights (both in one launch)
    k_pack_w2<<<(2 * C * C) / B, B, 0, stream>>>(W1, W2, W1p, W2p);

    // layer-1 GEMM: Hb1 = bf16(x @ W1)
    k_gemm_mfma<<<(n + 31) / 32, B, 0, stream>>>(x, W1p, Hb1, n);

    // fused: h_act1 = GELU(LN(agg(Hb1)+b1)); Hb2 = bf16(h_act1 @ W2)  (h_act1 never hits HBM)
    k_fused_agg_gemm<<<(n + 31) / 32, B, 0, stream>>>(rowbeg, rowcur, edata, Hb1, dis,
                                                      b1, g1, beta1, W2p, Hb2, n);

    // final: out = GELU(LN(agg(Hb2)+b2)) + x
    k_agg_ln_gelu<<<(n + 31) / 32, B, 0, stream>>>(rowbeg, rowcur, edata, Hb2, dis,
                                                   b2, g2, beta2, x, out, n);
}

// Round 10
// 184.867 us; speedup vs baseline: 1.0221x; 1.0221x over previous
//
#include <hip/hip_runtime.h>
#include <math.h>

#define C 128

typedef __attribute__((ext_vector_type(8))) short short8;
typedef __attribute__((ext_vector_type(4))) float f32x4;
typedef __attribute__((ext_vector_type(4))) unsigned short ushort4_t;
typedef __attribute__((ext_vector_type(8))) unsigned short ushort8_t;

__device__ inline unsigned short f2b(float f) {
    union { float f; unsigned int u; } v; v.f = f;
    unsigned int u = v.u;
    return (unsigned short)((u + 0x7FFFu + ((u >> 16) & 1u)) >> 16);  // RNE
}
__device__ inline float bits2f(unsigned int u) {
    union { unsigned int u; float f; } v; v.u = u; return v.f;
}

// accumulate 8 bf16 (packed in uint4) scaled by s into a[0..7]
__device__ inline void acc8(float* a, uint4 u, float s) {
    a[0] += s * bits2f(u.x << 16); a[1] += s * bits2f(u.x & 0xFFFF0000u);
    a[2] += s * bits2f(u.y << 16); a[3] += s * bits2f(u.y & 0xFFFF0000u);
    a[4] += s * bits2f(u.z << 16); a[5] += s * bits2f(u.z & 0xFFFF0000u);
    a[6] += s * bits2f(u.w << 16); a[7] += s * bits2f(u.w & 0xFFFF0000u);
}

// ---------------- shared row worker: aggregate + bias + LN + GELU ----------------
// 16 lanes cooperate on one row; this lane covers cols c0..c0+7. Result in t[8].
// 4-edge unroll: 4 independent edata loads then 4 independent row-gathers in flight.
__device__ inline void agg_ln_gelu_row(
    int row, int c0,
    const int* __restrict__ rowbeg, const int* __restrict__ rowend,
    const int2* __restrict__ edata, const unsigned short* __restrict__ Hb,
    const float* __restrict__ dis, const float* __restrict__ bias,
    const float* __restrict__ g, const float* __restrict__ beta, float* t) {
    float a[8] = {0.f, 0.f, 0.f, 0.f, 0.f, 0.f, 0.f, 0.f};

    // self-loop: dis^2 * Hb[row]
    {
        float d = dis[row];
        uint4 hu = *(const uint4*)(Hb + (size_t)row * C + c0);
        acc8(a, hu, d * d);
    }

    int ei = rowbeg[row];
    const int ee = rowend[row];
    for (; ei + 3 < ee; ei += 4) {
        int2 e0 = edata[ei];
        int2 e1 = edata[ei + 1];
        int2 e2 = edata[ei + 2];
        int2 e3 = edata[ei + 3];
        uint4 u0 = *(const uint4*)(Hb + (size_t)e0.x * C + c0);
        uint4 u1 = *(const uint4*)(Hb + (size_t)e1.x * C + c0);
        uint4 u2 = *(const uint4*)(Hb + (size_t)e2.x * C + c0);
        uint4 u3 = *(const uint4*)(Hb + (size_t)e3.x * C + c0);
        acc8(a, u0, bits2f((unsigned int)e0.y));
        acc8(a, u1, bits2f((unsigned int)e1.y));
        acc8(a, u2, bits2f((unsigned int)e2.y));
        acc8(a, u3, bits2f((unsigned int)e3.y));
    }
    for (; ei < ee; ++ei) {
        int2 e0 = edata[ei];
        uint4 u0 = *(const uint4*)(Hb + (size_t)e0.x * C + c0);
        acc8(a, u0, bits2f((unsigned int)e0.y));
    }

    // + bias
    float4 bv0 = *(const float4*)(bias + c0);
    float4 bv1 = *(const float4*)(bias + c0 + 4);
    a[0] += bv0.x; a[1] += bv0.y; a[2] += bv0.z; a[3] += bv0.w;
    a[4] += bv1.x; a[5] += bv1.y; a[6] += bv1.z; a[7] += bv1.w;

    // LayerNorm across the 16-lane group (128 cols)
    float s = 0.f, sq = 0.f;
    #pragma unroll
    for (int j = 0; j < 8; ++j) { s += a[j]; sq += a[j] * a[j]; }
    #pragma unroll
    for (int off = 8; off >= 1; off >>= 1) {
        s  += __shfl_xor(s, off, 64);
        sq += __shfl_xor(sq, off, 64);
    }
    float mu = s * (1.0f / C);
    float var = sq * (1.0f / C) - mu * mu;
    float rstd = rsqrtf(var + 1e-5f);

    float4 gv0 = *(const float4*)(g + c0);
    float4 gv1 = *(const float4*)(g + c0 + 4);
    float4 be0 = *(const float4*)(beta + c0);
    float4 be1 = *(const float4*)(beta + c0 + 4);
    float gg[8] = {gv0.x, gv0.y, gv0.z, gv0.w, gv1.x, gv1.y, gv1.z, gv1.w};
    float bb[8] = {be0.x, be0.y, be0.z, be0.w, be1.x, be1.y, be1.z, be1.w};

    #pragma unroll
    for (int j = 0; j < 8; ++j) {
        float v = (a[j] - mu) * rstd * gg[j] + bb[j];
        t[j] = 0.5f * v * (1.0f + erff(v * 0.70710678118654752f));
    }
}

// ---------------- gcn_norm + CSR build ----------------

__global__ void k_zero(int* __restrict__ cnt, int* __restrict__ cursor, int n) {
    int i = blockIdx.x * blockDim.x + threadIdx.x;
    if (i < n) cnt[i] = 0;
    if (i == 0) *cursor = 0;
}

__global__ void k_cnt(const int* __restrict__ dst, int* __restrict__ cnt, int e) {
    int i = blockIdx.x * blockDim.x + threadIdx.x;
    if (i < e) atomicAdd(&cnt[dst[i]], 1);
}

__global__ void k_dis_reserve(const int* __restrict__ cnt, float* __restrict__ dis,
                              int* __restrict__ rowbeg, int* __restrict__ rowcur,
                              int* __restrict__ cursor, int n) {
    int i = blockIdx.x * blockDim.x + threadIdx.x;
    if (i < n) {
        dis[i] = rsqrtf((float)cnt[i] + 1.0f);
        int b = atomicAdd(cursor, cnt[i]);
        rowbeg[i] = b;
        rowcur[i] = b;
    }
}

__global__ void k_place(const int* __restrict__ src, const int* __restrict__ dst,
                        const float* __restrict__ ew, const float* __restrict__ dis,
                        int* __restrict__ rowcur, int2* __restrict__ edata, int e) {
    int i = blockIdx.x * blockDim.x + threadIdx.x;
    if (i >= e) return;
    int s = src[i], d = dst[i];
    int p = atomicAdd(&rowcur[d], 1);
    float w = dis[s] * ew[i] * dis[d];
    union { float f; int i; } wb; wb.f = w;
    edata[p] = make_int2(s, wb.i);
}

// ---------------- W pack (both weights in one launch) ----------------
__global__ void k_pack_w2(const float* __restrict__ W1, const float* __restrict__ W2,
                          unsigned short* __restrict__ W1p, unsigned short* __restrict__ W2p) {
    int idx = blockIdx.x * blockDim.x + threadIdx.x;
    const float* W = (idx < C * C) ? W1 : W2;
    unsigned short* Wp = (idx < C * C) ? W1p : W2p;
    int p = idx & (C * C - 1);
    int j = p & 7;
    int l = (p >> 3) & 63;
    int t = p >> 9;           // ct*4 + ks
    int ks = t & 3, ct = t >> 2;
    int k = ks * 32 + ((l >> 4) << 3) + j;
    int c = (ct << 4) + (l & 15);
    Wp[p] = f2b(W[k * C + c]);
}

// ---------------- MFMA GEMM: Hb[n,128](bf16) = bf16(X[n,128]) @ Wp ----------------
__global__ __launch_bounds__(256) void k_gemm_mfma(
    const float* __restrict__ X, const unsigned short* __restrict__ Wp,
    unsigned short* __restrict__ Hb, int n) {
    __shared__ unsigned short xs[32 * C];  // 8 KB, XOR-swizzled
    const int tid = threadIdx.x;
    const int base = blockIdx.x * 32;

    const float4* Xv = (const float4*)(X + (size_t)base * C);
    #pragma unroll
    for (int i = 0; i < 4; ++i) {
        int idx4 = i * 256 + tid;
        int elem = idx4 * 4;
        int r = elem >> 7, c = elem & 127;
        float4 v = make_float4(0.f, 0.f, 0.f, 0.f);
        if (base + r < n) v = Xv[idx4];
        ushort4_t pkt;
        pkt.x = f2b(v.x); pkt.y = f2b(v.y); pkt.z = f2b(v.z); pkt.w = f2b(v.w);
        int byte = (r * 256 + c * 2) ^ ((r & 7) << 4);
        *(ushort4_t*)((char*)xs + byte) = pkt;
    }
    __syncthreads();

    const int lane = tid & 63;
    const int wid = tid >> 6;
    const int wm = wid >> 1;
    const int wn = wid & 1;
    const int arow = wm * 16 + (lane & 15);
    const int kg = lane >> 4;

    f32x4 acc[4] = {f32x4{0,0,0,0}, f32x4{0,0,0,0}, f32x4{0,0,0,0}, f32x4{0,0,0,0}};

    #pragma unroll
    for (int ks = 0; ks < 4; ++ks) {
        int abyte = (arow * 256 + ks * 64 + kg * 16) ^ ((arow & 7) << 4);
        short8 a = *(const short8*)((const char*)xs + abyte);
        #pragma unroll
        for (int nt = 0; nt < 4; ++nt) {
            int ct = wn * 4 + nt;
            short8 b = *(const short8*)(Wp + (size_t)((ct * 4 + ks) * 64 + lane) * 8);
            acc[nt] = __builtin_amdgcn_mfma_f32_16x16x32_bf16(a, b, acc[nt], 0, 0, 0);
        }
    }

    const int rbase = base + wm * 16 + kg * 4;
    #pragma unroll
    for (int nt = 0; nt < 4; ++nt) {
        int col = wn * 64 + nt * 16 + (lane & 15);
        #pragma unroll
        for (int r = 0; r < 4; ++r) {
            int row = rbase + r;
            if (row >= n) continue;
            Hb[(size_t)row * C + col] = f2b(acc[nt][r]);
        }
    }
}

// ---------------- fused: agg+bias+LN+GELU (layer-1 params) -> LDS -> GEMM (W2) ----------------
// 32 rows per block: phase A does 16 rows x 2 passes (16 lanes/row), phase B is the MFMA GEMM.
__global__ __launch_bounds__(256) void k_fused_agg_gemm(
    const int* __restrict__ rowbeg, const int* __restrict__ rowend,
    const int2* __restrict__ edata,
    const unsigned short* __restrict__ Hb_in, const float* __restrict__ dis,
    const float* __restrict__ bias, const float* __restrict__ g,
    const float* __restrict__ beta,
    const unsigned short* __restrict__ Wp, unsigned short* __restrict__ Hb_out, int n) {
    __shared__ unsigned short xs[32 * C];  // 8 KB, XOR-swizzled
    const int tid = threadIdx.x;
    const int lane = tid & 63;
    const int wid = tid >> 6;
    const int grp = lane >> 4;
    const int sub = lane & 15;
    const int base = blockIdx.x * 32;
    const int c0 = sub * 8;

    // phase A: aggregate + LN + GELU 32 rows, pack bf16 into swizzled LDS
    #pragma unroll
    for (int pass = 0; pass < 2; ++pass) {
        int r = pass * 16 + wid * 4 + grp;
        int row = base + r;
        float t[8] = {0.f, 0.f, 0.f, 0.f, 0.f, 0.f, 0.f, 0.f};
        if (row < n)
            agg_ln_gelu_row(row, c0, rowbeg, rowend, edata, Hb_in, dis, bias, g, beta, t);
        ushort8_t pkt;
        #pragma unroll
        for (int j = 0; j < 8; ++j) pkt[j] = f2b(t[j]);
        int byte = (r * 256 + c0 * 2) ^ ((r & 7) << 4);
        *(ushort8_t*)((char*)xs + byte) = pkt;
    }
    __syncthreads();

    // phase B: MFMA GEMM from LDS
    const int wm = wid >> 1;
    const int wn = wid & 1;
    const int arow = wm * 16 + (lane & 15);
    const int kg = lane >> 4;

    f32x4 acc[4] = {f32x4{0,0,0,0}, f32x4{0,0,0,0}, f32x4{0,0,0,0}, f32x4{0,0,0,0}};

    #pragma unroll
    for (int ks = 0; ks < 4; ++ks) {
        int abyte = (arow * 256 + ks * 64 + kg * 16) ^ ((arow & 7) << 4);
        short8 a = *(const short8*)((const char*)xs + abyte);
        #pragma unroll
        for (int nt = 0; nt < 4; ++nt) {
            int ct = wn * 4 + nt;
            short8 b = *(const short8*)(Wp + (size_t)((ct * 4 + ks) * 64 + lane) * 8);
            acc[nt] = __builtin_amdgcn_mfma_f32_16x16x32_bf16(a, b, acc[nt], 0, 0, 0);
        }
    }

    const int rbase = base + wm * 16 + kg * 4;
    #pragma unroll
    for (int nt = 0; nt < 4; ++nt) {
        int col = wn * 64 + nt * 16 + (lane & 15);
        #pragma unroll
        for (int r = 0; r < 4; ++r) {
            int row = rbase + r;
            if (row >= n) continue;
            Hb_out[(size_t)row * C + col] = f2b(acc[nt][r]);
        }
    }
}

// ---------------- final: aggregate + bias + LN + GELU + residual -> f32 out ----------------
// 16 lanes/row, 4 rows/wave, 16 rows/block.
__global__ __launch_bounds__(256) void k_agg_ln_gelu(
    const int* __restrict__ rowbeg, const int* __restrict__ rowend,
    const int2* __restrict__ edata,
    const unsigned short* __restrict__ Hb, const float* __restrict__ dis,
    const float* __restrict__ bias, const float* __restrict__ g,
    const float* __restrict__ beta, const float* __restrict__ resid,
    float* __restrict__ Out, int n) {
    const int lane = threadIdx.x & 63;
    const int wid = threadIdx.x >> 6;
    const int grp = lane >> 4;
    const int sub = lane & 15;
    const int row = blockIdx.x * 16 + wid * 4 + grp;
    if (row >= n) return;
    const int c0 = sub * 8;

    float t[8];
    agg_ln_gelu_row(row, c0, rowbeg, rowend, edata, Hb, dis, bias, g, beta, t);

    float4 r0 = *(const float4*)(resid + (size_t)row * C + c0);
    float4 r1 = *(const float4*)(resid + (size_t)row * C + c0 + 4);
    t[0] += r0.x; t[1] += r0.y; t[2] += r0.z; t[3] += r0.w;
    t[4] += r1.x; t[5] += r1.y; t[6] += r1.z; t[7] += r1.w;

    *(float4*)(Out + (size_t)row * C + c0) = make_float4(t[0], t[1], t[2], t[3]);
    *(float4*)(Out + (size_t)row * C + c0 + 4) = make_float4(t[4], t[5], t[6], t[7]);
}

// ---------------- launch ----------------

extern "C" void kernel_launch(void* const* d_in, const int* in_sizes, int n_in,
                              void* d_out, int out_size, void* d_ws, size_t ws_size,
                              hipStream_t stream) {
    const float* x      = (const float*)d_in[0];
    const int*   eidx   = (const int*)d_in[1];
    const float* ew     = (const float*)d_in[2];
    const float* W1     = (const float*)d_in[3];
    const float* b1     = (const float*)d_in[4];
    const float* g1     = (const float*)d_in[5];
    const float* beta1  = (const float*)d_in[6];
    const float* W2     = (const float*)d_in[7];
    const float* b2     = (const float*)d_in[8];
    const float* g2     = (const float*)d_in[9];
    const float* beta2  = (const float*)d_in[10];

    const int n = in_sizes[0] / C;
    const int e = in_sizes[2];
    const int* src = eidx;
    const int* dst = eidx + e;

    float* out = (float*)d_out;

    // workspace layout (256B-aligned chunks)
    char* p = (char*)d_ws;
    auto alloc = [&](size_t bytes) {
        char* q = p;
        p += (bytes + 255) & ~(size_t)255;
        return q;
    };
    float* dis    = (float*)alloc(sizeof(float) * n);
    int*   cnt    = (int*)alloc(sizeof(int) * n);
    int*   rowbeg = (int*)alloc(sizeof(int) * n);
    int*   rowcur = (int*)alloc(sizeof(int) * n);   // becomes rowend after k_place
    int2*  edata  = (int2*)alloc(sizeof(int2) * e);
    unsigned short* Hb1 = (unsigned short*)alloc(sizeof(unsigned short) * (size_t)n * C);
    unsigned short* Hb2 = (unsigned short*)alloc(sizeof(unsigned short) * (size_t)n * C);
    unsigned short* W1p = (unsigned short*)alloc(sizeof(unsigned short) * C * C);
    unsigned short* W2p = (unsigned short*)alloc(sizeof(unsigned short) * C * C);
    int*   cursor = (int*)alloc(sizeof(int));

    const int B = 256;
    const int gn = (n + B - 1) / B;
    const int ge = (e + B - 1) / B;

    // gcn_norm + CSR
    k_zero<<<gn, B, 0, stream>>>(cnt, cursor, n);
    k_cnt<<<ge, B, 0, stream>>>(dst, cnt, e);
    k_dis_reserve<<<gn, B, 0, stream>>>(cnt, dis, rowbeg, rowcur, cursor, n);
    k_place<<<ge, B, 0, stream>>>(src, dst, ew, dis, rowcur, edata, e);

    // pack weights (both in one launch)
    k_pack_w2<<<(2 * C * C) / B, B, 0, stream>>>(W1, W2, W1p, W2p);

    // layer-1 GEMM: Hb1 = bf16(x @ W1)
    k_gemm_mfma<<<(n + 31) / 32, B, 0, stream>>>(x, W1p, Hb1, n);

    // fused: h_act1 = GELU(LN(agg(Hb1)+b1)); Hb2 = bf16(h_act1 @ W2)  (h_act1 never hits HBM)
    k_fused_agg_gemm<<<(n + 31) / 32, B, 0, stream>>>(rowbeg, rowcur, edata, Hb1, dis,
                                                      b1, g1, beta1, W2p, Hb2, n);

    // final: out = GELU(LN(agg(Hb2)+b2)) + x
    k_agg_ln_gelu<<<(n + 15) / 16, B, 0, stream>>>(rowbeg, rowcur, edata, Hb2, dis,
                                                   b2, g2, beta2, x, out, n);
}